// Round 12
// baseline (317.820 us; speedup 1.0000x reference)
//
#include <hip/hip_runtime.h>

#define NUM_K 64
#define CDIM 32
#define HW 16384          // 128*128
#define NPTS 1048576      // 64*128*128
#define NELEMD 33554432.0 // 64*32*128*128

typedef float v2f __attribute__((ext_vector_type(2)));

// numpy pairwise sum of squares, n=32 contiguous: 8 accumulators + fixed tree.
__device__ __forceinline__ float np_sumsq32(const float* v) {
#pragma clang fp contract(off)
    float r[8];
    #pragma unroll
    for (int j = 0; j < 8; ++j) {
        float p0 = v[j] * v[j];
        float p1 = v[j + 8] * v[j + 8];
        float p2 = v[j + 16] * v[j + 16];
        float p3 = v[j + 24] * v[j + 24];
        r[j] = ((p0 + p1) + p2) + p3;
    }
    return ((r[0] + r[1]) + (r[2] + r[3])) + ((r[4] + r[5]) + (r[6] + r[7]));
}

__global__ void vq_prep(const float* __restrict__ emb, float* __restrict__ Bg,
                        float* __restrict__ embT) {
#pragma clang fp contract(off)
    int k = threadIdx.x;
    if (k < NUM_K) {
        float e[CDIM];
        #pragma unroll
        for (int c = 0; c < CDIM; ++c) e[c] = emb[k * CDIM + c];
        Bg[k] = np_sumsq32(e);
        #pragma unroll
        for (int c = 0; c < CDIM; ++c) embT[c * NUM_K + k] = e[c];
    }
}

// k split across WAVE PAIRS (not time): block = 256 threads = 128 points.
// Waves {0,2}: k in [0,32); waves {1,3}: k in [32,64) for the same points.
// Per-thread acc file halves to 32 VGPRs -> live ~60 < 64-VGPR quantum ->
// launch_bounds(256,8) is FEASIBLE (R11's spill came from an infeasible cap).
// x read twice per point (both waves, same CU -> L1); HBM unchanged.
__global__ __launch_bounds__(256, 8) void vq_main(const float* __restrict__ x,
                                                  const float* __restrict__ embT,
                                                  const float* __restrict__ Bg,
                                                  float* __restrict__ outq,
                                                  double* __restrict__ ws) {
#pragma clang fp contract(off)
    __shared__ float sET[CDIM][NUM_K];   // gather table (embT layout)
    __shared__ float sBest[2][2][64];    // [pair][half][lane]
    __shared__ int   sBi[2][2][64];
    __shared__ float sRed[4];

    const int t = threadIdx.x;
    #pragma unroll
    for (int i = t; i < NUM_K * CDIM; i += 256)
        ((float*)sET)[i] = embT[i];      // coalesced read, conflict-free write

    const int w = t >> 6;                // wave 0..3
    const int l = t & 63;
    const int pairI = w >> 1;            // point-group 0/1
    // kbase: wave-uniform in fact; readfirstlane pins it to SGPR so the
    // codebook row address stays scalar (s_load), not per-lane vector loads.
    const int kbase = __builtin_amdgcn_readfirstlane((w & 1) * 32);

    const int p = blockIdx.x * 128 + pairI * 64 + l;
    const int b = p >> 14;
    const size_t base = (size_t)b * (CDIM * HW) + (p & (HW - 1));
    const float* xp = x + base;

    v2f acc2[16];                        // k = kbase + 2q, 2q+1
    #pragma unroll
    for (int q = 0; q < 16; ++q) acc2[q] = (v2f){0.f, 0.f};
    float r[8];                          // numpy pairwise-tree partials for A

    #pragma unroll
    for (int g = 0; g < 4; ++g) {
        float xg[8];
        #pragma unroll
        for (int j = 0; j < 8; ++j)
            xg[j] = xp[(size_t)(g * 8 + j) * HW];   // 64 lanes = 64 consecutive pts
        #pragma unroll
        for (int j = 0; j < 8; ++j) {
            const int c = g * 8 + j;
            const float xc = xg[j];
            const float pp = xc * xc;               // rounds individually
            // r_j = ((p_j + p_{j+8}) + p_{j+16}) + p_{j+24} == numpy tree
            if (g == 0) r[j] = pp; else r[j] = r[j] + pp;
            const v2f xx = (v2f){xc, xc};
            const v2f* __restrict__ e2 = (const v2f*)(embT + c * NUM_K + kbase);
            #pragma unroll
            for (int q = 0; q < 16; ++q)
                acc2[q] = __builtin_elementwise_fma(xx, e2[q], acc2[q]);
        }
    }
    const float A = ((r[0] + r[1]) + (r[2] + r[3])) + ((r[4] + r[5]) + (r[6] + r[7]));

    // d_k = fmaf(-2, C_k, A+B_k) == fp32(fp32(A+B_k) - 2*C_k) bitwise; C_k is
    // the exact ascending-c fma chain of the passing R3..R10 kernels.
    // Ascending k + strict < => first-min within this half.
    float best = 3.4028235e38f;
    int bi = 0;
    #pragma unroll
    for (int q = 0; q < 16; ++q) {
        int k0 = kbase + 2 * q;
        float d0 = fmaf(-2.f, acc2[q].x, A + Bg[k0]);
        float d1 = fmaf(-2.f, acc2[q].y, A + Bg[k0 + 1]);
        if (d0 < best) { best = d0; bi = k0; }
        if (d1 < best) { best = d1; bi = k0 + 1; }
    }
    sBest[pairI][w & 1][l] = best;
    sBi[pairI][w & 1][l] = bi;
    __syncthreads();   // covers sET staging + pair combine

    float lsum = 0.f;
    if ((w & 1) == 0) {                  // low-half wave finishes the point
        float ob = sBest[pairI][1][l];
        int obi = sBi[pairI][1][l];
        if (ob < best) { best = ob; bi = obi; }   // strict <: low half wins ties
        float* op = outq + base;
        #pragma unroll
        for (int c = 0; c < CDIM; ++c)
            op[(size_t)c * HW] = sET[c][bi];      // coalesced 256B stores
        lsum = best;                              // loss contribution (validated R9)
    }

    #pragma unroll
    for (int off = 32; off > 0; off >>= 1)
        lsum += __shfl_down(lsum, off, 64);
    if ((t & 63) == 0) sRed[w] = lsum;
    __syncthreads();
    if (t == 0) {
        double bs = (double)sRed[0] + (double)sRed[1] + (double)sRed[2] + (double)sRed[3];
        atomicAdd(ws, bs);
    }
}

__global__ void vq_finish(const double* __restrict__ ws, float* __restrict__ loss) {
    loss[0] = (float)(1.25 * ws[0] / NELEMD);
}

extern "C" void kernel_launch(void* const* d_in, const int* in_sizes, int n_in,
                              void* d_out, int out_size, void* d_ws, size_t ws_size,
                              hipStream_t stream) {
    const float* x = (const float*)d_in[0];
    const float* emb = (const float*)d_in[1];
    float* out = (float*)d_out;
    // ws layout: [0,8) double loss acc; [64,320) Bg[64]; [320,8512) embT[32][64]
    double* acc = (double*)d_ws;
    float* Bg = (float*)((char*)d_ws + 64);
    float* embT = (float*)((char*)d_ws + 320);

    hipMemsetAsync(d_ws, 0, sizeof(double), stream);
    vq_prep<<<1, 64, 0, stream>>>(emb, Bg, embT);
    vq_main<<<NPTS / 128, 256, 0, stream>>>(x, embT, Bg, out + 1, acc);
    vq_finish<<<1, 1, 0, stream>>>(acc, out);
}

// Round 14
// 223.371 us; speedup vs baseline: 1.4228x; 1.4228x over previous
//
#include <hip/hip_runtime.h>

#define NUM_K 64
#define CDIM 32
#define HW 16384          // 128*128
#define NPTS 1048576      // 64*128*128
#define NELEMD 33554432.0 // 64*32*128*128

typedef float v2f __attribute__((ext_vector_type(2)));

// numpy pairwise sum of squares, n=32 contiguous: 8 accumulators + fixed tree.
__device__ __forceinline__ float np_sumsq32(const float* v) {
#pragma clang fp contract(off)
    float r[8];
    #pragma unroll
    for (int j = 0; j < 8; ++j) {
        float p0 = v[j] * v[j];
        float p1 = v[j + 8] * v[j + 8];
        float p2 = v[j + 16] * v[j + 16];
        float p3 = v[j + 24] * v[j + 24];
        r[j] = ((p0 + p1) + p2) + p3;
    }
    return ((r[0] + r[1]) + (r[2] + r[3])) + ((r[4] + r[5]) + (r[6] + r[7]));
}

__global__ void vq_prep(const float* __restrict__ emb, float* __restrict__ Bg,
                        float* __restrict__ embT) {
#pragma clang fp contract(off)
    int k = threadIdx.x;
    if (k < NUM_K) {
        float e[CDIM];
        #pragma unroll
        for (int c = 0; c < CDIM; ++c) e[c] = emb[k * CDIM + c];
        Bg[k] = np_sumsq32(e);
        #pragma unroll
        for (int c = 0; c < CDIM; ++c) embT[c * NUM_K + k] = e[c];
    }
}

// Quarter-k wave split: block = 4 waves over the SAME 64 points; wave h owns
// k in [16h, 16h+16) -> accumulator file = 16 VGPRs, total live ~45 << 64, so
// the (256,8) 64-reg / 32-wave-per-CU tier is comfortably feasible (R11/R12
// spilled because their live state exceeded the cap; this one can't).
// x staged once per block in LDS; sX[c][l] reads are 2-way bank-aliased (free).
__global__ __launch_bounds__(256, 8) void vq_main(const float* __restrict__ x,
                                                  const float* __restrict__ embT,
                                                  const float* __restrict__ Bg,
                                                  float* __restrict__ outq,
                                                  double* __restrict__ ws) {
#pragma clang fp contract(off)
    __shared__ float sX[CDIM * 64];      // [c][l]: this block's 64 points
    __shared__ float sET[CDIM * NUM_K];  // gather table (embT layout)
    __shared__ float sBest[4][64];       // [wave][lane]
    __shared__ int   sBi[4][64];

    const int t = threadIdx.x;
    const int w = t >> 6;                // wave 0..3
    const int l = t & 63;                // lane = point-in-group

    const int p0 = blockIdx.x * 64;      // 64 consecutive points; 64 | HW ->
    const int b = p0 >> 14;              // whole block in one image
    const size_t gbase = (size_t)b * (CDIM * HW) + (p0 & (HW - 1));

    // Stage x: 2048 floats, 8/thread; each wave-row is one 256B coalesced read;
    // linear LDS write = conflict-free.
    #pragma unroll
    for (int j = 0; j < 8; ++j) {
        int i = t + 256 * j;             // i = c*64 + wl
        sX[i] = x[gbase + (size_t)(i >> 6) * HW + (i & 63)];
    }
    #pragma unroll
    for (int i = t; i < NUM_K * CDIM; i += 256)
        sET[i] = embT[i];
    __syncthreads();

    // kbase is wave-uniform; pin to SGPR so codebook rows stay s_load.
    const int kbase = __builtin_amdgcn_readfirstlane(w << 4);

    v2f acc2[8];                         // k = kbase+2q, kbase+2q+1
    #pragma unroll
    for (int q = 0; q < 8; ++q) acc2[q] = (v2f){0.f, 0.f};
    float r[8];                          // numpy pairwise-tree partials for A

    #pragma unroll
    for (int c = 0; c < CDIM; ++c) {
        const float xc = sX[c * 64 + l];
        const float pp = xc * xc;        // rounds individually (contract off)
        // ascending-c left-assoc into partial c&7 == numpy tree
        if (c < 8) r[c] = pp; else r[c & 7] = r[c & 7] + pp;
        const v2f xx = (v2f){xc, xc};
        const v2f* __restrict__ e2 = (const v2f*)(embT + c * NUM_K + kbase);
        #pragma unroll
        for (int q = 0; q < 8; ++q)
            acc2[q] = __builtin_elementwise_fma(xx, e2[q], acc2[q]);
    }
    const float A = ((r[0] + r[1]) + (r[2] + r[3])) + ((r[4] + r[5]) + (r[6] + r[7]));

    // d_k = fmaf(-2, C_k, A+B_k) == fp32(fp32(A+B_k) - 2*C_k) bitwise; C_k is
    // the exact ascending-c fma chain of all passing rounds. Ascending k +
    // strict < => first-min within this wave's k-range.
    float best = 3.4028235e38f;
    int bi = 0;
    #pragma unroll
    for (int q = 0; q < 8; ++q) {
        int k0 = kbase + 2 * q;
        float d0 = fmaf(-2.f, acc2[q].x, A + Bg[k0]);
        float d1 = fmaf(-2.f, acc2[q].y, A + Bg[k0 + 1]);
        if (d0 < best) { best = d0; bi = k0; }
        if (d1 < best) { best = d1; bi = k0 + 1; }
    }
    sBest[w][l] = best;
    sBi[w][l] = bi;
    __syncthreads();

    if (w == 0) {                        // wave 0 finishes the 64 points
        // ascending wave order + strict < => global first-min (lower k wins ties)
        #pragma unroll
        for (int h = 1; h < 4; ++h) {
            float ob = sBest[h][l];
            int obi = sBi[h][l];
            if (ob < best) { best = ob; bi = obi; }
        }
        float* op = outq + gbase;
        #pragma unroll
        for (int c = 0; c < CDIM; ++c)
            op[(size_t)c * HW + l] = sET[c * 64 + bi];  // 256B coalesced stores

        float lsum = best;               // loss contribution (validated R9)
        #pragma unroll
        for (int off = 32; off > 0; off >>= 1)
            lsum += __shfl_down(lsum, off, 64);
        if (l == 0) atomicAdd(ws, (double)lsum);
    }
}

__global__ void vq_finish(const double* __restrict__ ws, float* __restrict__ loss) {
    loss[0] = (float)(1.25 * ws[0] / NELEMD);
}

extern "C" void kernel_launch(void* const* d_in, const int* in_sizes, int n_in,
                              void* d_out, int out_size, void* d_ws, size_t ws_size,
                              hipStream_t stream) {
    const float* x = (const float*)d_in[0];
    const float* emb = (const float*)d_in[1];
    float* out = (float*)d_out;
    // ws layout: [0,8) double loss acc; [64,320) Bg[64]; [320,8512) embT[32][64]
    double* acc = (double*)d_ws;
    float* Bg = (float*)((char*)d_ws + 64);
    float* embT = (float*)((char*)d_ws + 320);

    hipMemsetAsync(d_ws, 0, sizeof(double), stream);
    vq_prep<<<1, 64, 0, stream>>>(emb, Bg, embT);
    vq_main<<<NPTS / 64, 256, 0, stream>>>(x, embT, Bg, out + 1, acc);
    vq_finish<<<1, 1, 0, stream>>>(acc, out);
}